// Round 4
// baseline (868.504 us; speedup 1.0000x reference)
//
#include <hip/hip_runtime.h>
#include <math.h>

#define NOSC 2048
#define NB 16
#define DT 0.1f
#define M_TOT (NB * NOSC)    // 32768
#define ITILE 8              // i-columns per block
#define NJL 32               // j-lanes per thread row

// Workspace: two R buffers, each [32][NOSC] floats (rows 0..15 sin, 16..31 cos).
// R_cur is read-only within a step; R_next written disjointly per block.

// ---------- init: copy theta and build R buffer 0 ----------
__global__ void init_kernel(const float* __restrict__ th_in,
                            float* __restrict__ th,
                            float* __restrict__ R0) {
    int o = blockIdx.x * blockDim.x + threadIdx.x;   // o = b*NOSC + j
    if (o < M_TOT) {
        float v = th_in[o];
        th[o] = v;
        float s, c;
        sincosf(v, &s, &c);
        R0[o] = s;              // sin row b
        R0[M_TOT + o] = c;      // cos row 16+b
    }
}

// ---------- fused step: full-dot GEMM + theta update, one dispatch ----------
// grid = NOSC/ITILE = 256 blocks, block = 256 threads.
// thread: jl = t&31 (j-lane), il = t>>5 (i-offset). i = bx*8 + il.
// Each thread: acc[c] = sum over j in {jl*4+128k} of Rcur[c][j]*K[i][j].
// Block-level jl-reduction in LDS, then threads t<128 update theta(b, i).
template <bool FINAL>
__global__ __launch_bounds__(256) void step_kernel(
        const float* __restrict__ Kmat,
        const float* __restrict__ Rcur,
        float* __restrict__ Rnext,
        const float* __restrict__ omega,
        const float* __restrict__ kg,
        const float* __restrict__ mod,
        float* __restrict__ th) {
    const int t = threadIdx.x;
    const int jl = t & (NJL - 1);
    const int il = t >> 5;
    const int i0 = blockIdx.x * ITILE;
    const int i = i0 + il;

    const float* __restrict__ Krow = Kmat + (size_t)i * NOSC;

    float acc[32];
#pragma unroll
    for (int c = 0; c < 32; ++c) acc[c] = 0.0f;

    for (int k = 0; k < NOSC / (NJL * 4); ++k) {   // 16 iters
        const int j = jl * 4 + k * (NJL * 4);
        const float4 kv = *reinterpret_cast<const float4*>(Krow + j);
#pragma unroll
        for (int c = 0; c < 32; ++c) {
            const float4 rv = *reinterpret_cast<const float4*>(Rcur + (size_t)c * NOSC + j);
            acc[c] = fmaf(rv.x, kv.x, acc[c]);
            acc[c] = fmaf(rv.y, kv.y, acc[c]);
            acc[c] = fmaf(rv.z, kv.z, acc[c]);
            acc[c] = fmaf(rv.w, kv.w, acc[c]);
        }
    }

    // ---- block reduction over jl ----
    __shared__ float lds[NJL][ITILE][36];   // padded row (36 floats, 16B-aligned)
    __shared__ float coup[32][ITILE];

#pragma unroll
    for (int c4 = 0; c4 < 8; ++c4) {
        float4 v = make_float4(acc[c4 * 4], acc[c4 * 4 + 1],
                               acc[c4 * 4 + 2], acc[c4 * 4 + 3]);
        *reinterpret_cast<float4*>(&lds[jl][il][c4 * 4]) = v;
    }
    __syncthreads();

    {
        const int c = t >> 3;        // 0..31
        const int ilr = t & 7;       // 0..7
        float s = 0.0f;
#pragma unroll 8
        for (int q = 0; q < NJL; ++q) s += lds[q][ilr][c];
        coup[c][ilr] = s;
    }
    __syncthreads();

    // ---- theta update for this block's (b, i) outputs ----
    if (t < NB * ITILE) {
        const int b = t >> 3;        // 0..15
        const int ilr = t & 7;
        const int iu = i0 + ilr;
        const float aS = coup[b][ilr];
        const float aC = coup[NB + b][ilr];

        const float sin_i = Rcur[(size_t)b * NOSC + iu];
        const float cos_i = Rcur[(size_t)(NB + b) * NOSC + iu];
        const float scale = kg[0] * (1.0f + mod[0]) * (1.0f / (float)NOSC);
        const float coupling = cos_i * aS - sin_i * aC;

        const size_t o = (size_t)b * NOSC + iu;
        float nt = th[o] + DT * (omega[iu] + scale * coupling);
        float ws, wc;
        sincosf(nt, &ws, &wc);
        // wrap only changes theta by 2*pi*k -> sin/cos unchanged; defer atan2
        th[o] = FINAL ? atan2f(ws, wc) : nt;
        Rnext[o] = ws;
        Rnext[M_TOT + o] = wc;
    }
}

// ---------- coherence from final R ----------
__global__ void coherence_kernel(const float* __restrict__ R,
                                 float* __restrict__ coh) {
    const int b = blockIdx.x;
    const int t = threadIdx.x;
    float ss = 0.0f, sc = 0.0f;
    for (int j = t; j < NOSC; j += 256) {
        ss += R[(size_t)b * NOSC + j];
        sc += R[M_TOT + (size_t)b * NOSC + j];
    }
    for (int off = 32; off > 0; off >>= 1) {
        ss += __shfl_down(ss, off);
        sc += __shfl_down(sc, off);
    }
    __shared__ float red[8];
    const int w = t >> 6;
    if ((t & 63) == 0) { red[w * 2] = sc; red[w * 2 + 1] = ss; }
    __syncthreads();
    if (t == 0) {
        float tc = 0.0f, ts = 0.0f;
        for (int k = 0; k < 4; ++k) { tc += red[k * 2]; ts += red[k * 2 + 1]; }
        tc /= (float)NOSC;
        ts /= (float)NOSC;
        coh[b] = sqrtf(tc * tc + ts * ts);
    }
}

extern "C" void kernel_launch(void* const* d_in, const int* in_sizes, int n_in,
                              void* d_out, int out_size, void* d_ws, size_t ws_size,
                              hipStream_t stream) {
    const float* theta_in = (const float*)d_in[0];
    const float* Kmat     = (const float*)d_in[1];
    const float* omega    = (const float*)d_in[2];
    const float* kg       = (const float*)d_in[3];
    const float* mod      = (const float*)d_in[4];

    float* th  = (float*)d_out;               // [NB][NOSC] final theta
    float* coh = (float*)d_out + M_TOT;       // [NB]
    float* Rb[2];
    Rb[0] = (float*)d_ws;                     // [32][NOSC]
    Rb[1] = (float*)d_ws + 2 * M_TOT;         // [32][NOSC]

    init_kernel<<<(M_TOT + 255) / 256, 256, 0, stream>>>(theta_in, th, Rb[0]);

    for (int s = 0; s < 10; ++s) {
        const float* Rc = Rb[s & 1];
        float* Rn = Rb[(s + 1) & 1];
        if (s < 9)
            step_kernel<false><<<NOSC / ITILE, 256, 0, stream>>>(
                Kmat, Rc, Rn, omega, kg, mod, th);
        else
            step_kernel<true><<<NOSC / ITILE, 256, 0, stream>>>(
                Kmat, Rc, Rn, omega, kg, mod, th);
    }

    // after 10 steps current buffer is Rb[10 & 1] = Rb[0]
    coherence_kernel<<<NB, 256, 0, stream>>>(Rb[0], coh);
}

// Round 5
// 500.419 us; speedup vs baseline: 1.7356x; 1.7356x over previous
//
#include <hip/hip_runtime.h>
#include <hip/hip_cooperative_groups.h>
#include <math.h>

namespace cgx = cooperative_groups;

#define NOSC 2048
#define NB 16
#define DT 0.1f
#define M_TOT (NB * NOSC)    // 32768
#define ITILE 8              // i-columns per block
#define NBLK (NOSC / ITILE)  // 256 blocks = 1 per CU
#define NTHR 1024            // 16 waves per block

// Workspace: two R buffers, each [32][NOSC] (rows 0..15 sin(theta[b]), 16..31 cos).

// Shared step body: block blk computes coupling for i in [blk*8, blk*8+8),
// all 32 (sin/cos x batch) rows, full j; then updates theta for its 128 (b,i).
// Thread layout: jl = t&31 (j-lane), cg = (t>>5)&7 (4 c's), ig = t>>8 (2 i's).
__device__ __forceinline__ void step_compute(
    const float* __restrict__ Kmat,
    const float* __restrict__ Rcur,
    float* __restrict__ Rnext,
    const float* __restrict__ omega,
    float scale,
    float* __restrict__ th,
    int blk, int t, bool final_step,
    float* __restrict__ coup)   // LDS [32*ITILE]
{
    const int jl = t & 31;
    const int cg = (t >> 5) & 7;
    const int ig = t >> 8;
    const int i0 = blk * ITILE;
    const int ia = i0 + ig * 2;

    const float* __restrict__ Ka = Kmat + (size_t)ia * NOSC;
    const float* __restrict__ Kb = Ka + NOSC;
    const float* __restrict__ Rb0 = Rcur + (size_t)(cg * 4) * NOSC;

    float acc[4][2];
#pragma unroll
    for (int cc = 0; cc < 4; ++cc) { acc[cc][0] = 0.0f; acc[cc][1] = 0.0f; }

#pragma unroll 4
    for (int k = 0; k < 16; ++k) {
        const int j = jl * 4 + k * 128;
        const float4 kva = *reinterpret_cast<const float4*>(Ka + j);
        const float4 kvb = *reinterpret_cast<const float4*>(Kb + j);
#pragma unroll
        for (int cc = 0; cc < 4; ++cc) {
            const float4 rv = *reinterpret_cast<const float4*>(Rb0 + (size_t)cc * NOSC + j);
            acc[cc][0] = fmaf(rv.x, kva.x, acc[cc][0]);
            acc[cc][0] = fmaf(rv.y, kva.y, acc[cc][0]);
            acc[cc][0] = fmaf(rv.z, kva.z, acc[cc][0]);
            acc[cc][0] = fmaf(rv.w, kva.w, acc[cc][0]);
            acc[cc][1] = fmaf(rv.x, kvb.x, acc[cc][1]);
            acc[cc][1] = fmaf(rv.y, kvb.y, acc[cc][1]);
            acc[cc][1] = fmaf(rv.z, kvb.z, acc[cc][1]);
            acc[cc][1] = fmaf(rv.w, kvb.w, acc[cc][1]);
        }
    }

    // reduce over the 32 j-lanes (masks <32 stay within each 32-lane half-wave)
#pragma unroll
    for (int cc = 0; cc < 4; ++cc)
#pragma unroll
        for (int ii = 0; ii < 2; ++ii) {
            float v = acc[cc][ii];
            v += __shfl_xor(v, 1);
            v += __shfl_xor(v, 2);
            v += __shfl_xor(v, 4);
            v += __shfl_xor(v, 8);
            v += __shfl_xor(v, 16);
            acc[cc][ii] = v;
        }

    if (jl == 0) {
#pragma unroll
        for (int cc = 0; cc < 4; ++cc)
#pragma unroll
            for (int ii = 0; ii < 2; ++ii)
                coup[(cg * 4 + cc) * ITILE + (ig * 2 + ii)] = acc[cc][ii];
    }
    __syncthreads();

    if (t < NB * ITILE) {
        const int b = t & 15;
        const int il = t >> 4;
        const int i = i0 + il;
        const float aS = coup[b * ITILE + il];
        const float aC = coup[(NB + b) * ITILE + il];
        const size_t o = (size_t)b * NOSC + i;
        const float sin_i = Rcur[o];
        const float cos_i = Rcur[M_TOT + o];
        float nt = th[o] + DT * (omega[i] + scale * (cos_i * aS - sin_i * aC));
        float ws, wc;
        sincosf(nt, &ws, &wc);
        // wrap only shifts theta by 2*pi*k -> sin/cos unchanged; defer atan2 to last step
        th[o] = final_step ? atan2f(ws, wc) : nt;
        Rnext[o] = ws;
        Rnext[M_TOT + o] = wc;
    }
    __syncthreads();   // coup is rewritten next step (coop path)
}

// ---------------- cooperative whole-problem kernel ----------------
__global__ __launch_bounds__(NTHR) void coop_kernel(
    const float* __restrict__ theta_in,
    const float* __restrict__ Kmat,
    const float* __restrict__ omega,
    const float* __restrict__ kg,
    const float* __restrict__ mod,
    float* __restrict__ th,
    float* __restrict__ coh,
    float* __restrict__ R0,
    float* __restrict__ R1)
{
    __shared__ float coup[32 * ITILE];
    cgx::grid_group grid = cgx::this_grid();
    const int blk = blockIdx.x;
    const int t = threadIdx.x;
    const int gid = blk * NTHR + t;

    // init: copy theta, build R0
    if (gid < M_TOT) {
        float v = theta_in[gid];
        th[gid] = v;
        float s, c;
        sincosf(v, &s, &c);
        R0[gid] = s;
        R0[M_TOT + gid] = c;
    }
    const float scale = kg[0] * (1.0f + mod[0]) * (1.0f / (float)NOSC);
    grid.sync();

    for (int s = 0; s < 10; ++s) {
        const float* rc = (s & 1) ? R1 : R0;
        float* rn = (s & 1) ? R0 : R1;
        step_compute(Kmat, rc, rn, omega, scale, th, blk, t, s == 9, coup);
        grid.sync();
    }

    // coherence from R0 (step 9 wrote R0); blocks 0..15, one per batch
    if (blk < NB) {
        const float* __restrict__ Rf = R0;
        float ss = 0.0f, sc = 0.0f;
        for (int j = t; j < NOSC; j += NTHR) {
            ss += Rf[(size_t)blk * NOSC + j];
            sc += Rf[M_TOT + (size_t)blk * NOSC + j];
        }
#pragma unroll
        for (int off = 32; off > 0; off >>= 1) {
            ss += __shfl_down(ss, off);
            sc += __shfl_down(sc, off);
        }
        const int w = t >> 6;                 // 16 waves
        if ((t & 63) == 0) { coup[w * 2] = sc; coup[w * 2 + 1] = ss; }
        __syncthreads();
        if (t == 0) {
            float tc = 0.0f, ts = 0.0f;
            for (int k = 0; k < 16; ++k) { tc += coup[k * 2]; ts += coup[k * 2 + 1]; }
            tc /= (float)NOSC;
            ts /= (float)NOSC;
            coh[blk] = sqrtf(tc * tc + ts * ts);
        }
    }
}

// ---------------- non-cooperative fallback ----------------
__global__ void init_kernel(const float* __restrict__ th_in,
                            float* __restrict__ th,
                            float* __restrict__ R0) {
    int o = blockIdx.x * blockDim.x + threadIdx.x;
    if (o < M_TOT) {
        float v = th_in[o];
        th[o] = v;
        float s, c;
        sincosf(v, &s, &c);
        R0[o] = s;
        R0[M_TOT + o] = c;
    }
}

template <bool FINAL>
__global__ __launch_bounds__(NTHR) void step_nc_kernel(
    const float* __restrict__ Kmat,
    const float* __restrict__ Rcur,
    float* __restrict__ Rnext,
    const float* __restrict__ omega,
    const float* __restrict__ kg,
    const float* __restrict__ mod,
    float* __restrict__ th)
{
    __shared__ float coup[32 * ITILE];
    const float scale = kg[0] * (1.0f + mod[0]) * (1.0f / (float)NOSC);
    step_compute(Kmat, Rcur, Rnext, omega, scale, th,
                 blockIdx.x, threadIdx.x, FINAL, coup);
}

__global__ void coherence_kernel(const float* __restrict__ R,
                                 float* __restrict__ coh) {
    const int b = blockIdx.x;
    const int t = threadIdx.x;
    float ss = 0.0f, sc = 0.0f;
    for (int j = t; j < NOSC; j += 256) {
        ss += R[(size_t)b * NOSC + j];
        sc += R[M_TOT + (size_t)b * NOSC + j];
    }
    for (int off = 32; off > 0; off >>= 1) {
        ss += __shfl_down(ss, off);
        sc += __shfl_down(sc, off);
    }
    __shared__ float red[8];
    const int w = t >> 6;
    if ((t & 63) == 0) { red[w * 2] = sc; red[w * 2 + 1] = ss; }
    __syncthreads();
    if (t == 0) {
        float tc = 0.0f, ts = 0.0f;
        for (int k = 0; k < 4; ++k) { tc += red[k * 2]; ts += red[k * 2 + 1]; }
        tc /= (float)NOSC;
        ts /= (float)NOSC;
        coh[b] = sqrtf(tc * tc + ts * ts);
    }
}

extern "C" void kernel_launch(void* const* d_in, const int* in_sizes, int n_in,
                              void* d_out, int out_size, void* d_ws, size_t ws_size,
                              hipStream_t stream) {
    const float* theta_in = (const float*)d_in[0];
    const float* Kmat     = (const float*)d_in[1];
    const float* omega    = (const float*)d_in[2];
    const float* kg       = (const float*)d_in[3];
    const float* mod      = (const float*)d_in[4];

    float* th  = (float*)d_out;               // [NB][NOSC] final theta
    float* coh = (float*)d_out + M_TOT;       // [NB]
    float* R0  = (float*)d_ws;                // [2*M_TOT]
    float* R1  = (float*)d_ws + 2 * M_TOT;    // [2*M_TOT]

    void* args[] = {(void*)&theta_in, (void*)&Kmat, (void*)&omega,
                    (void*)&kg, (void*)&mod,
                    (void*)&th, (void*)&coh, (void*)&R0, (void*)&R1};
    hipError_t err = hipLaunchCooperativeKernel((const void*)coop_kernel,
                                                dim3(NBLK), dim3(NTHR),
                                                args, 0, stream);
    if (err != hipSuccess) {
        // fallback: same math, one dispatch per step
        init_kernel<<<(M_TOT + 255) / 256, 256, 0, stream>>>(theta_in, th, R0);
        for (int s = 0; s < 10; ++s) {
            const float* rc = (s & 1) ? R1 : R0;
            float* rn = (s & 1) ? R0 : R1;
            if (s < 9)
                step_nc_kernel<false><<<NBLK, NTHR, 0, stream>>>(
                    Kmat, rc, rn, omega, kg, mod, th);
            else
                step_nc_kernel<true><<<NBLK, NTHR, 0, stream>>>(
                    Kmat, rc, rn, omega, kg, mod, th);
        }
        coherence_kernel<<<NB, 256, 0, stream>>>(R0, coh);
    }
}

// Round 6
// 188.730 us; speedup vs baseline: 4.6018x; 2.6515x over previous
//
#include <hip/hip_runtime.h>
#include <math.h>

#define NOSC 2048
#define NB 16
#define DT 0.1f
#define M_TOT (NB * NOSC)    // 32768
#define ITILE 8              // i-columns per block
#define NBLK (NOSC / ITILE)  // 256 blocks
#define NTHR 1024            // 16 waves per block

// Workspace: two R buffers, each [32][NOSC] (rows 0..15 sin(theta[b]), 16..31 cos).
// Dispatch boundary = global barrier (grid.sync measured ~45us/sync on gfx950 —
// software barrier spins through L3 across non-coherent XCD L2s; dispatch is ~2us).

// ---------- init: copy theta and build R0 ----------
__global__ void init_kernel(const float* __restrict__ th_in,
                            float* __restrict__ th,
                            float* __restrict__ R0) {
    int o = blockIdx.x * blockDim.x + threadIdx.x;   // o = b*NOSC + j
    if (o < M_TOT) {
        float v = th_in[o];
        th[o] = v;
        float s, c;
        sincosf(v, &s, &c);
        R0[o] = s;
        R0[M_TOT + o] = c;
    }
}

// ---------- fused step: GEMM over full j + theta update, one dispatch ----------
// Block blk owns i in [blk*8, blk*8+8), all 32 (sin/cos x batch) c-rows.
// Thread: jl = t&31 (j-lane), cg = (t>>5)&7 (4 c's), ig = t>>8 (2 i's).
// Per k-iter: 2 K float4 + 4 R float4 loads -> 32 FMAs (5.3:1 FMA:load).
// jl-reduction via 5 shfl_xor (stays within 32-lane half-wave), no LDS conflicts.
template <bool FINAL>
__global__ __launch_bounds__(NTHR) void step_kernel(
    const float* __restrict__ Kmat,
    const float* __restrict__ Rcur,
    float* __restrict__ Rnext,
    const float* __restrict__ omega,
    const float* __restrict__ kg,
    const float* __restrict__ mod,
    float* __restrict__ th)
{
    __shared__ float coup[32 * ITILE];
    const int t = threadIdx.x;
    const int jl = t & 31;
    const int cg = (t >> 5) & 7;
    const int ig = t >> 8;
    const int i0 = blockIdx.x * ITILE;
    const int ia = i0 + ig * 2;

    const float* __restrict__ Ka = Kmat + (size_t)ia * NOSC;
    const float* __restrict__ Kb = Ka + NOSC;
    const float* __restrict__ Rb0 = Rcur + (size_t)(cg * 4) * NOSC;

    float acc[4][2];
#pragma unroll
    for (int cc = 0; cc < 4; ++cc) { acc[cc][0] = 0.0f; acc[cc][1] = 0.0f; }

#pragma unroll 4
    for (int k = 0; k < 16; ++k) {
        const int j = jl * 4 + k * 128;
        const float4 kva = *reinterpret_cast<const float4*>(Ka + j);
        const float4 kvb = *reinterpret_cast<const float4*>(Kb + j);
#pragma unroll
        for (int cc = 0; cc < 4; ++cc) {
            const float4 rv = *reinterpret_cast<const float4*>(Rb0 + (size_t)cc * NOSC + j);
            acc[cc][0] = fmaf(rv.x, kva.x, acc[cc][0]);
            acc[cc][0] = fmaf(rv.y, kva.y, acc[cc][0]);
            acc[cc][0] = fmaf(rv.z, kva.z, acc[cc][0]);
            acc[cc][0] = fmaf(rv.w, kva.w, acc[cc][0]);
            acc[cc][1] = fmaf(rv.x, kvb.x, acc[cc][1]);
            acc[cc][1] = fmaf(rv.y, kvb.y, acc[cc][1]);
            acc[cc][1] = fmaf(rv.z, kvb.z, acc[cc][1]);
            acc[cc][1] = fmaf(rv.w, kvb.w, acc[cc][1]);
        }
    }

#pragma unroll
    for (int cc = 0; cc < 4; ++cc)
#pragma unroll
        for (int ii = 0; ii < 2; ++ii) {
            float v = acc[cc][ii];
            v += __shfl_xor(v, 1);
            v += __shfl_xor(v, 2);
            v += __shfl_xor(v, 4);
            v += __shfl_xor(v, 8);
            v += __shfl_xor(v, 16);
            acc[cc][ii] = v;
        }

    if (jl == 0) {
#pragma unroll
        for (int cc = 0; cc < 4; ++cc)
#pragma unroll
            for (int ii = 0; ii < 2; ++ii)
                coup[(cg * 4 + cc) * ITILE + (ig * 2 + ii)] = acc[cc][ii];
    }
    __syncthreads();

    if (t < NB * ITILE) {
        const int b = t & 15;
        const int il = t >> 4;
        const int i = i0 + il;
        const float aS = coup[b * ITILE + il];
        const float aC = coup[(NB + b) * ITILE + il];
        const size_t o = (size_t)b * NOSC + i;
        const float sin_i = Rcur[o];
        const float cos_i = Rcur[M_TOT + o];
        const float scale = kg[0] * (1.0f + mod[0]) * (1.0f / (float)NOSC);
        float nt = th[o] + DT * (omega[i] + scale * (cos_i * aS - sin_i * aC));
        float ws, wc;
        sincosf(nt, &ws, &wc);
        // wrap only shifts theta by 2*pi*k -> sin/cos unchanged; defer atan2 to last step
        th[o] = FINAL ? atan2f(ws, wc) : nt;
        Rnext[o] = ws;
        Rnext[M_TOT + o] = wc;
    }
}

// ---------- coherence from final R ----------
__global__ void coherence_kernel(const float* __restrict__ R,
                                 float* __restrict__ coh) {
    const int b = blockIdx.x;
    const int t = threadIdx.x;
    float ss = 0.0f, sc = 0.0f;
    for (int j = t; j < NOSC; j += 256) {
        ss += R[(size_t)b * NOSC + j];
        sc += R[M_TOT + (size_t)b * NOSC + j];
    }
    for (int off = 32; off > 0; off >>= 1) {
        ss += __shfl_down(ss, off);
        sc += __shfl_down(sc, off);
    }
    __shared__ float red[8];
    const int w = t >> 6;
    if ((t & 63) == 0) { red[w * 2] = sc; red[w * 2 + 1] = ss; }
    __syncthreads();
    if (t == 0) {
        float tc = 0.0f, ts = 0.0f;
        for (int k = 0; k < 4; ++k) { tc += red[k * 2]; ts += red[k * 2 + 1]; }
        tc /= (float)NOSC;
        ts /= (float)NOSC;
        coh[b] = sqrtf(tc * tc + ts * ts);
    }
}

extern "C" void kernel_launch(void* const* d_in, const int* in_sizes, int n_in,
                              void* d_out, int out_size, void* d_ws, size_t ws_size,
                              hipStream_t stream) {
    const float* theta_in = (const float*)d_in[0];
    const float* Kmat     = (const float*)d_in[1];
    const float* omega    = (const float*)d_in[2];
    const float* kg       = (const float*)d_in[3];
    const float* mod      = (const float*)d_in[4];

    float* th  = (float*)d_out;               // [NB][NOSC] final theta
    float* coh = (float*)d_out + M_TOT;       // [NB]
    float* R0  = (float*)d_ws;                // [2*M_TOT]
    float* R1  = (float*)d_ws + 2 * M_TOT;    // [2*M_TOT]

    init_kernel<<<(M_TOT + 255) / 256, 256, 0, stream>>>(theta_in, th, R0);

    for (int s = 0; s < 10; ++s) {
        const float* rc = (s & 1) ? R1 : R0;
        float* rn = (s & 1) ? R0 : R1;
        if (s < 9)
            step_kernel<false><<<NBLK, NTHR, 0, stream>>>(
                Kmat, rc, rn, omega, kg, mod, th);
        else
            step_kernel<true><<<NBLK, NTHR, 0, stream>>>(
                Kmat, rc, rn, omega, kg, mod, th);
    }

    // after 10 steps the live buffer is R0
    coherence_kernel<<<NB, 256, 0, stream>>>(R0, coh);
}

// Round 7
// 156.793 us; speedup vs baseline: 5.5392x; 1.2037x over previous
//
#include <hip/hip_runtime.h>
#include <math.h>

#define NOSC 2048
#define NB 16
#define DT 0.1f
#define M_TOT (NB * NOSC)    // 32768
#define ITILE 8              // i-columns per block
#define NBLK (NOSC / ITILE)  // 256 blocks
#define NTHR 1024            // 16 waves per block (1 block/CU)

// Workspace: two R buffers, each [32][NOSC] (rows 0..15 sin(theta[b]), 16..31 cos).

// ---------- init: copy theta and build R0 ----------
__global__ void init_kernel(const float* __restrict__ th_in,
                            float* __restrict__ th,
                            float* __restrict__ R0) {
    int o = blockIdx.x * blockDim.x + threadIdx.x;   // o = b*NOSC + j
    if (o < M_TOT) {
        float v = th_in[o];
        th[o] = v;
        float s, c;
        sincosf(v, &s, &c);
        R0[o] = s;
        R0[M_TOT + o] = c;
    }
}

// ---------- fused step: K-tile in LDS + GEMM + theta update ----------
// Block blk owns i in [blk*8, blk*8+8), all 32 (sin/cos x batch) c-rows.
// Thread: jl = t&31 (j-lane), cg = (t>>5)&7 (4 c's), ig = t>>8 (2 i's).
// K tile (8 rows x 2048 = 64 KB) staged to LDS once; inner loop reads K from
// LDS (wave-uniform row -> conflict-free b128) + 4 R float4 from global.
// __launch_bounds__(1024,4): 1 block/CU, VGPR cap 128 -> loads pipeline.
template <bool FINAL>
__global__ __launch_bounds__(NTHR, 4) void step_kernel(
    const float* __restrict__ Kmat,
    const float* __restrict__ Rcur,
    float* __restrict__ Rnext,
    const float* __restrict__ omega,
    const float* __restrict__ kg,
    const float* __restrict__ mod,
    float* __restrict__ th)
{
    __shared__ float Kt[ITILE * NOSC];      // 64 KB
    __shared__ float coup[32 * ITILE];

    const int t = threadIdx.x;
    const int i0 = blockIdx.x * ITILE;

    // stage K tile: 8 consecutive rows are one contiguous 64 KB span
    {
        const float4* __restrict__ Ksrc =
            reinterpret_cast<const float4*>(Kmat + (size_t)i0 * NOSC);
        float4* KtV = reinterpret_cast<float4*>(Kt);
#pragma unroll
        for (int o = 0; o < ITILE * NOSC / 4 / NTHR; ++o)   // 4 per thread
            KtV[t + o * NTHR] = Ksrc[t + o * NTHR];
    }
    __syncthreads();

    const int jl = t & 31;
    const int cg = (t >> 5) & 7;
    const int ig = t >> 8;

    const float* __restrict__ Ka = Kt + (size_t)(ig * 2) * NOSC;
    const float* __restrict__ Kb = Ka + NOSC;
    const float* __restrict__ Rb0 = Rcur + (size_t)(cg * 4) * NOSC;

    float acc[4][2];
#pragma unroll
    for (int cc = 0; cc < 4; ++cc) { acc[cc][0] = 0.0f; acc[cc][1] = 0.0f; }

#pragma unroll 4
    for (int k = 0; k < 16; ++k) {
        const int j = jl * 4 + k * 128;
        const float4 kva = *reinterpret_cast<const float4*>(Ka + j);
        const float4 kvb = *reinterpret_cast<const float4*>(Kb + j);
#pragma unroll
        for (int cc = 0; cc < 4; ++cc) {
            const float4 rv = *reinterpret_cast<const float4*>(Rb0 + (size_t)cc * NOSC + j);
            acc[cc][0] = fmaf(rv.x, kva.x, acc[cc][0]);
            acc[cc][0] = fmaf(rv.y, kva.y, acc[cc][0]);
            acc[cc][0] = fmaf(rv.z, kva.z, acc[cc][0]);
            acc[cc][0] = fmaf(rv.w, kva.w, acc[cc][0]);
            acc[cc][1] = fmaf(rv.x, kvb.x, acc[cc][1]);
            acc[cc][1] = fmaf(rv.y, kvb.y, acc[cc][1]);
            acc[cc][1] = fmaf(rv.z, kvb.z, acc[cc][1]);
            acc[cc][1] = fmaf(rv.w, kvb.w, acc[cc][1]);
        }
    }

    // reduce over the 32 j-lanes (stays within each 32-lane half-wave)
#pragma unroll
    for (int cc = 0; cc < 4; ++cc)
#pragma unroll
        for (int ii = 0; ii < 2; ++ii) {
            float v = acc[cc][ii];
            v += __shfl_xor(v, 1);
            v += __shfl_xor(v, 2);
            v += __shfl_xor(v, 4);
            v += __shfl_xor(v, 8);
            v += __shfl_xor(v, 16);
            acc[cc][ii] = v;
        }

    if (jl == 0) {
#pragma unroll
        for (int cc = 0; cc < 4; ++cc)
#pragma unroll
            for (int ii = 0; ii < 2; ++ii)
                coup[(cg * 4 + cc) * ITILE + (ig * 2 + ii)] = acc[cc][ii];
    }
    __syncthreads();

    if (t < NB * ITILE) {
        const int b = t & 15;
        const int il = t >> 4;
        const int i = i0 + il;
        const float aS = coup[b * ITILE + il];
        const float aC = coup[(NB + b) * ITILE + il];
        const size_t o = (size_t)b * NOSC + i;
        const float sin_i = Rcur[o];
        const float cos_i = Rcur[M_TOT + o];
        const float scale = kg[0] * (1.0f + mod[0]) * (1.0f / (float)NOSC);
        float nt = th[o] + DT * (omega[i] + scale * (cos_i * aS - sin_i * aC));
        float ws, wc;
        sincosf(nt, &ws, &wc);
        // wrap only shifts theta by 2*pi*k -> sin/cos unchanged; defer atan2
        th[o] = FINAL ? atan2f(ws, wc) : nt;
        Rnext[o] = ws;
        Rnext[M_TOT + o] = wc;
    }
}

// ---------- coherence from final R ----------
__global__ void coherence_kernel(const float* __restrict__ R,
                                 float* __restrict__ coh) {
    const int b = blockIdx.x;
    const int t = threadIdx.x;
    float ss = 0.0f, sc = 0.0f;
    for (int j = t; j < NOSC; j += 256) {
        ss += R[(size_t)b * NOSC + j];
        sc += R[M_TOT + (size_t)b * NOSC + j];
    }
    for (int off = 32; off > 0; off >>= 1) {
        ss += __shfl_down(ss, off);
        sc += __shfl_down(sc, off);
    }
    __shared__ float red[8];
    const int w = t >> 6;
    if ((t & 63) == 0) { red[w * 2] = sc; red[w * 2 + 1] = ss; }
    __syncthreads();
    if (t == 0) {
        float tc = 0.0f, ts = 0.0f;
        for (int k = 0; k < 4; ++k) { tc += red[k * 2]; ts += red[k * 2 + 1]; }
        tc /= (float)NOSC;
        ts /= (float)NOSC;
        coh[b] = sqrtf(tc * tc + ts * ts);
    }
}

extern "C" void kernel_launch(void* const* d_in, const int* in_sizes, int n_in,
                              void* d_out, int out_size, void* d_ws, size_t ws_size,
                              hipStream_t stream) {
    const float* theta_in = (const float*)d_in[0];
    const float* Kmat     = (const float*)d_in[1];
    const float* omega    = (const float*)d_in[2];
    const float* kg       = (const float*)d_in[3];
    const float* mod      = (const float*)d_in[4];

    float* th  = (float*)d_out;               // [NB][NOSC] final theta
    float* coh = (float*)d_out + M_TOT;       // [NB]
    float* R0  = (float*)d_ws;                // [2*M_TOT]
    float* R1  = (float*)d_ws + 2 * M_TOT;    // [2*M_TOT]

    init_kernel<<<(M_TOT + 255) / 256, 256, 0, stream>>>(theta_in, th, R0);

    for (int s = 0; s < 10; ++s) {
        const float* rc = (s & 1) ? R1 : R0;
        float* rn = (s & 1) ? R0 : R1;
        if (s < 9)
            step_kernel<false><<<NBLK, NTHR, 0, stream>>>(
                Kmat, rc, rn, omega, kg, mod, th);
        else
            step_kernel<true><<<NBLK, NTHR, 0, stream>>>(
                Kmat, rc, rn, omega, kg, mod, th);
    }

    // after 10 steps the live buffer is R0
    coherence_kernel<<<NB, 256, 0, stream>>>(R0, coh);
}

// Round 8
// 115.866 us; speedup vs baseline: 7.4958x; 1.3532x over previous
//
#include <hip/hip_runtime.h>
#include <math.h>

#define NOSC 2048
#define NB 16
#define DT 0.1f
#define M_TOT (NB * NOSC)    // 32768
#define ITILE 8              // i-columns per block
#define NTHR 256             // 4 waves; 2 blocks/CU
#define NBLK 512             // 256 i-tiles x 2 batch-halves

// Workspace: two R buffers, each [32][NOSC] (rows 0..15 sin(theta[b]), 16..31 cos).

// ---------- init: copy theta and build R0 ----------
__global__ void init_kernel(const float* __restrict__ th_in,
                            float* __restrict__ th,
                            float* __restrict__ R0) {
    int o = blockIdx.x * blockDim.x + threadIdx.x;   // o = b*NOSC + j
    if (o < M_TOT) {
        float v = th_in[o];
        th[o] = v;
        float s, c;
        sincosf(v, &s, &c);
        R0[o] = s;
        R0[M_TOT + o] = c;
    }
}

// ---------- fused step ----------
// Block bx: i-tile it = bx&255 (i in [it*8, it*8+8)), batch-half h = bx>>8.
// Covers 16 c-rows: slots 0..7 = sin of b = h*8+s, slots 8..15 = cos of same b
// -> theta update for these 64 (b,i) stays fused in-block.
// Thread: jl = t&31, cgr = (t>>5)&3 (4 slots each), igr = t>>7 (4 i's each).
// Per j-chunk: 4 K b128 (LDS, same addr for both wave halves -> broadcast)
//            + 4 R float4 (global, L2-resident) -> 64 FMA. acc[4][4]=16 VGPR.
template <bool FINAL>
__global__ __launch_bounds__(NTHR, 2) void step_kernel(
    const float* __restrict__ Kmat,
    const float* __restrict__ Rcur,
    float* __restrict__ Rnext,
    const float* __restrict__ omega,
    const float* __restrict__ kg,
    const float* __restrict__ mod,
    float* __restrict__ th)
{
    __shared__ float Kt[ITILE * NOSC];      // 64 KB
    __shared__ float coup[16 * ITILE];

    const int t = threadIdx.x;
    const int it = blockIdx.x & 255;
    const int h  = blockIdx.x >> 8;         // same i-tile pair -> same XCD
    const int i0 = it * ITILE;

    // stage K tile (8 consecutive rows = contiguous 64 KB), coalesced
    {
        const float4* __restrict__ Ksrc =
            reinterpret_cast<const float4*>(Kmat + (size_t)i0 * NOSC);
        float4* KtV = reinterpret_cast<float4*>(Kt);
#pragma unroll
        for (int o = 0; o < ITILE * NOSC / 4 / NTHR; ++o)   // 16 per thread
            KtV[t + o * NTHR] = Ksrc[t + o * NTHR];
    }
    __syncthreads();

    const int jl = t & 31;
    const int cgr = (t >> 5) & 3;
    const int igr = t >> 7;                 // 0..1

    // R row pointers for this thread's 4 c-slots
    const float* __restrict__ Rrow[4];
#pragma unroll
    for (int cc = 0; cc < 4; ++cc) {
        const int s = cgr * 4 + cc;                       // 0..15
        const int c = h * 8 + (s & 7) + ((s >> 3) << 4);  // sin rows then cos rows
        Rrow[cc] = Rcur + (size_t)c * NOSC;
    }
    const float* __restrict__ Kb = Kt + (size_t)(igr * 4) * NOSC;

    float acc[4][4];
#pragma unroll
    for (int cc = 0; cc < 4; ++cc)
#pragma unroll
        for (int ii = 0; ii < 4; ++ii) acc[cc][ii] = 0.0f;

#pragma unroll 4
    for (int k = 0; k < 16; ++k) {
        const int j = jl * 4 + k * 128;
        float4 kv[4];
#pragma unroll
        for (int ii = 0; ii < 4; ++ii)
            kv[ii] = *reinterpret_cast<const float4*>(Kb + (size_t)ii * NOSC + j);
#pragma unroll
        for (int cc = 0; cc < 4; ++cc) {
            const float4 rv = *reinterpret_cast<const float4*>(Rrow[cc] + j);
#pragma unroll
            for (int ii = 0; ii < 4; ++ii) {
                acc[cc][ii] = fmaf(rv.x, kv[ii].x, acc[cc][ii]);
                acc[cc][ii] = fmaf(rv.y, kv[ii].y, acc[cc][ii]);
                acc[cc][ii] = fmaf(rv.z, kv[ii].z, acc[cc][ii]);
                acc[cc][ii] = fmaf(rv.w, kv[ii].w, acc[cc][ii]);
            }
        }
    }

    // reduce over the 32 j-lanes (xor masks <=16 stay within 32-lane halves)
#pragma unroll
    for (int cc = 0; cc < 4; ++cc)
#pragma unroll
        for (int ii = 0; ii < 4; ++ii) {
            float v = acc[cc][ii];
            v += __shfl_xor(v, 1);
            v += __shfl_xor(v, 2);
            v += __shfl_xor(v, 4);
            v += __shfl_xor(v, 8);
            v += __shfl_xor(v, 16);
            acc[cc][ii] = v;
        }

    if (jl == 0) {
#pragma unroll
        for (int cc = 0; cc < 4; ++cc)
#pragma unroll
            for (int ii = 0; ii < 4; ++ii)
                coup[(cgr * 4 + cc) * ITILE + (igr * 4 + ii)] = acc[cc][ii];
    }
    __syncthreads();

    // theta update for this block's 64 (b,i)
    if (t < 8 * ITILE) {
        const int br = t >> 3;             // 0..7
        const int il = t & 7;
        const int b = h * 8 + br;
        const int i = i0 + il;
        const float aS = coup[br * ITILE + il];
        const float aC = coup[(8 + br) * ITILE + il];
        const size_t o = (size_t)b * NOSC + i;
        const float sin_i = Rcur[o];
        const float cos_i = Rcur[M_TOT + o];
        const float scale = kg[0] * (1.0f + mod[0]) * (1.0f / (float)NOSC);
        float nt = th[o] + DT * (omega[i] + scale * (cos_i * aS - sin_i * aC));
        float ws, wc;
        sincosf(nt, &ws, &wc);
        // wrap only shifts theta by 2*pi*k -> sin/cos unchanged; defer atan2
        th[o] = FINAL ? atan2f(ws, wc) : nt;
        Rnext[o] = ws;
        Rnext[M_TOT + o] = wc;
    }
}

// ---------- coherence from final R ----------
__global__ void coherence_kernel(const float* __restrict__ R,
                                 float* __restrict__ coh) {
    const int b = blockIdx.x;
    const int t = threadIdx.x;
    float ss = 0.0f, sc = 0.0f;
    for (int j = t; j < NOSC; j += 256) {
        ss += R[(size_t)b * NOSC + j];
        sc += R[M_TOT + (size_t)b * NOSC + j];
    }
    for (int off = 32; off > 0; off >>= 1) {
        ss += __shfl_down(ss, off);
        sc += __shfl_down(sc, off);
    }
    __shared__ float red[8];
    const int w = t >> 6;
    if ((t & 63) == 0) { red[w * 2] = sc; red[w * 2 + 1] = ss; }
    __syncthreads();
    if (t == 0) {
        float tc = 0.0f, ts = 0.0f;
        for (int k = 0; k < 4; ++k) { tc += red[k * 2]; ts += red[k * 2 + 1]; }
        tc /= (float)NOSC;
        ts /= (float)NOSC;
        coh[b] = sqrtf(tc * tc + ts * ts);
    }
}

extern "C" void kernel_launch(void* const* d_in, const int* in_sizes, int n_in,
                              void* d_out, int out_size, void* d_ws, size_t ws_size,
                              hipStream_t stream) {
    const float* theta_in = (const float*)d_in[0];
    const float* Kmat     = (const float*)d_in[1];
    const float* omega    = (const float*)d_in[2];
    const float* kg       = (const float*)d_in[3];
    const float* mod      = (const float*)d_in[4];

    float* th  = (float*)d_out;               // [NB][NOSC] final theta
    float* coh = (float*)d_out + M_TOT;       // [NB]
    float* R0  = (float*)d_ws;                // [2*M_TOT]
    float* R1  = (float*)d_ws + 2 * M_TOT;    // [2*M_TOT]

    init_kernel<<<(M_TOT + 255) / 256, 256, 0, stream>>>(theta_in, th, R0);

    for (int s = 0; s < 10; ++s) {
        const float* rc = (s & 1) ? R1 : R0;
        float* rn = (s & 1) ? R0 : R1;
        if (s < 9)
            step_kernel<false><<<NBLK, NTHR, 0, stream>>>(
                Kmat, rc, rn, omega, kg, mod, th);
        else
            step_kernel<true><<<NBLK, NTHR, 0, stream>>>(
                Kmat, rc, rn, omega, kg, mod, th);
    }

    // after 10 steps the live buffer is R0
    coherence_kernel<<<NB, 256, 0, stream>>>(R0, coh);
}

// Round 9
// 109.334 us; speedup vs baseline: 7.9436x; 1.0597x over previous
//
#include <hip/hip_runtime.h>
#include <math.h>

#define NOSC 2048
#define NB 16
#define DT 0.1f
#define M_TOT (NB * NOSC)    // 32768

typedef __attribute__((ext_vector_type(8))) short bf16x8;
typedef __attribute__((ext_vector_type(4))) float f32x4;

__device__ __forceinline__ unsigned short f2bf(float x) {
    unsigned int u = __float_as_uint(x);
    u += 0x7FFFu + ((u >> 16) & 1u);          // round-to-nearest-even
    return (unsigned short)(u >> 16);
}
__device__ __forceinline__ float bf2f(unsigned short u) {
    return __uint_as_float(((unsigned int)u) << 16);
}

// ws layout: Kb[2048][2048] bf16 (8 MB) | R0 [32][2048] bf16 (128 KB) | R1 (128 KB)
// R rows 0..15 = sin(theta[b][:]), rows 16..31 = cos.

// ---------- prep: convert K to bf16 (blocks 0..2047) + init theta/R0 (blocks 2048..2079)
__global__ void prep_kernel(const float* __restrict__ Kmat,
                            const float* __restrict__ th_in,
                            float* __restrict__ th,
                            unsigned short* __restrict__ Kb,
                            unsigned short* __restrict__ R0) {
    const int bx = blockIdx.x;
    const int t = threadIdx.x;
    if (bx < NOSC) {
        const float4* __restrict__ src =
            reinterpret_cast<const float4*>(Kmat + (size_t)bx * NOSC);
        unsigned short* __restrict__ dst = Kb + (size_t)bx * NOSC;
#pragma unroll
        for (int o = 0; o < 2; ++o) {
            const int q = t + o * 256;           // 0..511 float4s
            float4 v = src[q];
            ushort4 u;
            u.x = f2bf(v.x); u.y = f2bf(v.y); u.z = f2bf(v.z); u.w = f2bf(v.w);
            *reinterpret_cast<ushort4*>(dst + q * 4) = u;
        }
    } else {
        const int o4 = ((bx - NOSC) * 256 + t) * 4;   // 4 elems per thread
        if (o4 < M_TOT) {
            float4 v = *reinterpret_cast<const float4*>(th_in + o4);
            *reinterpret_cast<float4*>(th + o4) = v;
            float s0, c0, s1, c1, s2, c2, s3, c3;
            sincosf(v.x, &s0, &c0); sincosf(v.y, &s1, &c1);
            sincosf(v.z, &s2, &c2); sincosf(v.w, &s3, &c3);
            ushort4 us = {f2bf(s0), f2bf(s1), f2bf(s2), f2bf(s3)};
            ushort4 uc = {f2bf(c0), f2bf(c1), f2bf(c2), f2bf(c3)};
            *reinterpret_cast<ushort4*>(R0 + o4) = us;
            *reinterpret_cast<ushort4*>(R0 + M_TOT + o4) = uc;
        }
    }
}

// ---------- fused MFMA step ----------
// Block = 16 i-columns (i0 = bx*16), 512 threads = 8 waves.
// Wave w: half = w>>2 (0: A rows = sin rows 0..15, 1: cos rows 16..31),
//         kq = w&3 (k-quarter of 512).
// D[c][i] = sum_k A[c][k] * B[k][i];  B[k][i] = K[k][i] = K[i][k] (symmetric)
// -> both fragments are contiguous bf16x8 row reads.
// mfma_f32_16x16x32_bf16: A lane: row=lane&15, k=(lane>>4)*8+e (contiguous 8);
//                         B lane: col=lane&15, k=(lane>>4)*8+e;
//                         D lane: col=lane&15, row=(lane>>4)*4+reg.
template <bool FINAL>
__global__ __launch_bounds__(512, 2) void step_kernel(
    const unsigned short* __restrict__ Kb,
    const unsigned short* __restrict__ Rc,
    unsigned short* __restrict__ Rn,
    const float* __restrict__ omega,
    const float* __restrict__ kg,
    const float* __restrict__ mod,
    float* __restrict__ th)
{
    __shared__ float part[8][64][4];     // 8 KB: [wave][lane][reg]
    __shared__ float coup[32][16];       // 2 KB

    const int t = threadIdx.x;
    const int lane = t & 63;
    const int w = t >> 6;
    const int kq = w & 3;
    const int half = w >> 2;
    const int i0 = blockIdx.x * 16;

    const int row_a = half * 16 + (lane & 15);
    const int row_b = i0 + (lane & 15);
    const int kbase = kq * 512 + ((lane >> 4) << 3);

    const unsigned short* __restrict__ pa = Rc + (size_t)row_a * NOSC + kbase;
    const unsigned short* __restrict__ pb = Kb + (size_t)row_b * NOSC + kbase;

    f32x4 acc = {0.0f, 0.0f, 0.0f, 0.0f};
#pragma unroll
    for (int it = 0; it < 16; ++it) {
        bf16x8 a = *reinterpret_cast<const bf16x8*>(pa + it * 32);
        bf16x8 b = *reinterpret_cast<const bf16x8*>(pb + it * 32);
        acc = __builtin_amdgcn_mfma_f32_16x16x32_bf16(a, b, acc, 0, 0, 0);
    }
    *reinterpret_cast<f32x4*>(&part[w][lane][0]) = acc;
    __syncthreads();

    // gather partials: C[c][il], c = half*16 + 4*(lane>>4) + reg
    {
        const int c = t >> 4;            // 0..31
        const int il = t & 15;
        const int h2 = c >> 4;
        const int cl = c & 15;
        const int ln = ((cl >> 2) << 4) | il;
        const int rg = cl & 3;
        float s = 0.0f;
#pragma unroll
        for (int q = 0; q < 4; ++q) s += part[h2 * 4 + q][ln][rg];
        coup[c][il] = s;
    }
    __syncthreads();

    // theta update for this block's 256 (b, i)
    if (t < 256) {
        const int b = t >> 4;
        const int il = t & 15;
        const int i = i0 + il;
        const float aS = coup[b][il];
        const float aC = coup[16 + b][il];
        const size_t o = (size_t)b * NOSC + i;
        const float sin_i = bf2f(Rc[o]);
        const float cos_i = bf2f(Rc[M_TOT + o]);
        const float scale = kg[0] * (1.0f + mod[0]) * (1.0f / (float)NOSC);
        float nt = th[o] + DT * (omega[i] + scale * (cos_i * aS - sin_i * aC));
        float ws, wc;
        sincosf(nt, &ws, &wc);
        // wrap only shifts theta by 2*pi*k -> sin/cos unchanged; defer atan2
        th[o] = FINAL ? atan2f(ws, wc) : nt;
        Rn[o] = f2bf(ws);
        Rn[M_TOT + o] = f2bf(wc);
    }
}

// ---------- coherence from final R (bf16) ----------
__global__ void coherence_kernel(const unsigned short* __restrict__ R,
                                 float* __restrict__ coh) {
    const int b = blockIdx.x;
    const int t = threadIdx.x;
    float ss = 0.0f, sc = 0.0f;
    for (int j = t; j < NOSC; j += 256) {
        ss += bf2f(R[(size_t)b * NOSC + j]);
        sc += bf2f(R[M_TOT + (size_t)b * NOSC + j]);
    }
    for (int off = 32; off > 0; off >>= 1) {
        ss += __shfl_down(ss, off);
        sc += __shfl_down(sc, off);
    }
    __shared__ float red[8];
    const int w = t >> 6;
    if ((t & 63) == 0) { red[w * 2] = sc; red[w * 2 + 1] = ss; }
    __syncthreads();
    if (t == 0) {
        float tc = 0.0f, ts = 0.0f;
        for (int k = 0; k < 4; ++k) { tc += red[k * 2]; ts += red[k * 2 + 1]; }
        tc /= (float)NOSC;
        ts /= (float)NOSC;
        coh[b] = sqrtf(tc * tc + ts * ts);
    }
}

extern "C" void kernel_launch(void* const* d_in, const int* in_sizes, int n_in,
                              void* d_out, int out_size, void* d_ws, size_t ws_size,
                              hipStream_t stream) {
    const float* theta_in = (const float*)d_in[0];
    const float* Kmat     = (const float*)d_in[1];
    const float* omega    = (const float*)d_in[2];
    const float* kg       = (const float*)d_in[3];
    const float* mod      = (const float*)d_in[4];

    float* th  = (float*)d_out;               // [NB][NOSC] final theta
    float* coh = (float*)d_out + M_TOT;       // [NB]

    unsigned short* Kb = (unsigned short*)d_ws;                       // 8 MB
    unsigned short* R0 = (unsigned short*)d_ws + (size_t)NOSC * NOSC; // 128 KB
    unsigned short* R1 = R0 + 2 * M_TOT;                              // 128 KB

    // blocks 0..2047 convert K rows; blocks 2048..2079 init theta/R0
    prep_kernel<<<NOSC + 32, 256, 0, stream>>>(Kmat, theta_in, th, Kb, R0);

    for (int s = 0; s < 10; ++s) {
        const unsigned short* rc = (s & 1) ? R1 : R0;
        unsigned short* rn = (s & 1) ? R0 : R1;
        if (s < 9)
            step_kernel<false><<<NOSC / 16, 512, 0, stream>>>(
                Kb, rc, rn, omega, kg, mod, th);
        else
            step_kernel<true><<<NOSC / 16, 512, 0, stream>>>(
                Kb, rc, rn, omega, kg, mod, th);
    }

    // after 10 steps the live buffer is R0
    coherence_kernel<<<NB, 256, 0, stream>>>(R0, coh);
}

// Round 10
// 94.020 us; speedup vs baseline: 9.2375x; 1.1629x over previous
//
#include <hip/hip_runtime.h>
#include <math.h>

#define NOSC 2048
#define NB 16
#define DT 0.1f
#define M_TOT (NB * NOSC)    // 32768
#define KTP 2056             // padded LDS K row (breaks bank alignment)

typedef __attribute__((ext_vector_type(8))) short bf16x8;
typedef __attribute__((ext_vector_type(4))) float f32x4;

__device__ __forceinline__ unsigned short f2bf(float x) {
    unsigned int u = __float_as_uint(x);
    u += 0x7FFFu + ((u >> 16) & 1u);          // round-to-nearest-even
    return (unsigned short)(u >> 16);
}
__device__ __forceinline__ float bf2f(unsigned short u) {
    return __uint_as_float(((unsigned int)u) << 16);
}

// ws layout: Kb[2048][2048] bf16 (8 MB) | R0 [32][2048] bf16 | R1
// R rows 0..15 = sin(theta[b][:]), rows 16..31 = cos.

// ---------- init: copy theta, build R0 (32 blocks x 256) ----------
__global__ void init_kernel(const float* __restrict__ th_in,
                            float* __restrict__ th,
                            unsigned short* __restrict__ R0) {
    const int o4 = (blockIdx.x * 256 + threadIdx.x) * 4;
    if (o4 < M_TOT) {
        float4 v = *reinterpret_cast<const float4*>(th_in + o4);
        *reinterpret_cast<float4*>(th + o4) = v;
        float s0, c0, s1, c1, s2, c2, s3, c3;
        sincosf(v.x, &s0, &c0); sincosf(v.y, &s1, &c1);
        sincosf(v.z, &s2, &c2); sincosf(v.w, &s3, &c3);
        ushort4 us = {f2bf(s0), f2bf(s1), f2bf(s2), f2bf(s3)};
        ushort4 uc = {f2bf(c0), f2bf(c1), f2bf(c2), f2bf(c3)};
        *reinterpret_cast<ushort4*>(R0 + o4) = us;
        *reinterpret_cast<ushort4*>(R0 + M_TOT + o4) = uc;
    }
}

// ---------- fused MFMA step ----------
// Grid 128, block 1024 = 16 waves. Block owns i in [bx*16, bx*16+16).
// Wave w = kq (k-sixteenth, 128 k = 4 MFMA iters of K=32). Each wave computes
// BOTH c-halves (sin rows 0..15 / cos rows 16..31) sharing one B fragment:
// 2 independent 4-deep MFMA chains, 3 loads per iter, 1-deep preload pipeline.
// FIRST: convert this block's 16 K rows f32->bf16 into LDS (B source) and
// write-through to global Kb for later steps.
// mfma_f32_16x16x32_bf16: A lane row=lane&15, k=(lane>>4)*8+e;
//                         B lane col=lane&15, same k; D col=lane&15,
//                         row=(lane>>4)*4+reg.
template <bool FIRST, bool FINAL>
__global__ __launch_bounds__(1024, 4) void step_kernel(
    const float* __restrict__ Kmat,
    unsigned short* __restrict__ Kb,
    const unsigned short* __restrict__ Rc,
    unsigned short* __restrict__ Rn,
    const float* __restrict__ omega,
    const float* __restrict__ kg,
    const float* __restrict__ mod,
    float* __restrict__ th)
{
    __shared__ float part[16][2][64][4];            // 32 KB
    __shared__ float coup[32][16];                  // 2 KB
    __shared__ unsigned short Kt[16][KTP];          // 64.25 KB (FIRST only)

    const int t = threadIdx.x;
    const int lane = t & 63;
    const int w = t >> 6;                            // wave = kq, 0..15
    const int i0 = blockIdx.x * 16;

    if constexpr (FIRST) {
        // convert this block's K tile (16 rows x 2048 f32 = 128 KB, contiguous)
        const float4* __restrict__ src =
            reinterpret_cast<const float4*>(Kmat + (size_t)i0 * NOSC);
#pragma unroll
        for (int p = 0; p < 8; ++p) {
            const int q = t + p * 1024;              // float4 index 0..8191
            float4 v = src[q];
            ushort4 u = {f2bf(v.x), f2bf(v.y), f2bf(v.z), f2bf(v.w)};
            const int row = q >> 9;
            const int col = (q & 511) * 4;
            *reinterpret_cast<ushort4*>(&Kt[row][col]) = u;
            *reinterpret_cast<ushort4*>(Kb + (size_t)(i0 + row) * NOSC + col) = u;
        }
        __syncthreads();
    }

    const int rl = lane & 15;
    const int kbase = w * 128 + ((lane >> 4) << 3);

    const unsigned short* __restrict__ pas = Rc + (size_t)rl * NOSC + kbase;
    const unsigned short* __restrict__ pac = Rc + (size_t)(16 + rl) * NOSC + kbase;
    const unsigned short* __restrict__ pbg = Kb + (size_t)(i0 + rl) * NOSC + kbase;

    auto loadB = [&](int it) -> bf16x8 {
        if constexpr (FIRST)
            return *reinterpret_cast<const bf16x8*>(&Kt[rl][kbase + it * 32]);
        else
            return *reinterpret_cast<const bf16x8*>(pbg + it * 32);
    };

    f32x4 acc_s = {0.0f, 0.0f, 0.0f, 0.0f};
    f32x4 acc_c = {0.0f, 0.0f, 0.0f, 0.0f};

    bf16x8 b  = loadB(0);
    bf16x8 as = *reinterpret_cast<const bf16x8*>(pas);
    bf16x8 ac = *reinterpret_cast<const bf16x8*>(pac);
#pragma unroll
    for (int it = 0; it < 4; ++it) {
        bf16x8 bn = b, asn = as, acn = ac;
        if (it < 3) {
            bn  = loadB(it + 1);
            asn = *reinterpret_cast<const bf16x8*>(pas + (it + 1) * 32);
            acn = *reinterpret_cast<const bf16x8*>(pac + (it + 1) * 32);
        }
        acc_s = __builtin_amdgcn_mfma_f32_16x16x32_bf16(as, b, acc_s, 0, 0, 0);
        acc_c = __builtin_amdgcn_mfma_f32_16x16x32_bf16(ac, b, acc_c, 0, 0, 0);
        b = bn; as = asn; ac = acn;
    }

    *reinterpret_cast<f32x4*>(&part[w][0][lane][0]) = acc_s;
    *reinterpret_cast<f32x4*>(&part[w][1][lane][0]) = acc_c;
    __syncthreads();

    // reduce 16 kq-partials: cell (c, il), c = half*16 + (ln>>4)*4 + rg
    if (t < 512) {
        const int c = t >> 4;            // 0..31
        const int il = t & 15;
        const int half = c >> 4;
        const int cl = c & 15;
        const int ln = ((cl >> 2) << 4) | il;
        const int rg = cl & 3;
        float s = 0.0f;
#pragma unroll
        for (int q = 0; q < 16; ++q) s += part[q][half][ln][rg];
        coup[c][il] = s;
    }
    __syncthreads();

    // theta update for this block's 256 (b, i)
    if (t < 256) {
        const int b2 = t >> 4;
        const int il = t & 15;
        const int i = i0 + il;
        const float aS = coup[b2][il];
        const float aC = coup[16 + b2][il];
        const size_t o = (size_t)b2 * NOSC + i;
        const float sin_i = bf2f(Rc[o]);
        const float cos_i = bf2f(Rc[M_TOT + o]);
        const float scale = kg[0] * (1.0f + mod[0]) * (1.0f / (float)NOSC);
        float nt = th[o] + DT * (omega[i] + scale * (cos_i * aS - sin_i * aC));
        float ws, wc;
        sincosf(nt, &ws, &wc);
        // wrap only shifts theta by 2*pi*k -> sin/cos unchanged; defer atan2
        th[o] = FINAL ? atan2f(ws, wc) : nt;
        Rn[o] = f2bf(ws);
        Rn[M_TOT + o] = f2bf(wc);
    }
}

// ---------- coherence from final R (bf16) ----------
__global__ void coherence_kernel(const unsigned short* __restrict__ R,
                                 float* __restrict__ coh) {
    const int b = blockIdx.x;
    const int t = threadIdx.x;
    float ss = 0.0f, sc = 0.0f;
    for (int j = t; j < NOSC; j += 256) {
        ss += bf2f(R[(size_t)b * NOSC + j]);
        sc += bf2f(R[M_TOT + (size_t)b * NOSC + j]);
    }
    for (int off = 32; off > 0; off >>= 1) {
        ss += __shfl_down(ss, off);
        sc += __shfl_down(sc, off);
    }
    __shared__ float red[8];
    const int w = t >> 6;
    if ((t & 63) == 0) { red[w * 2] = sc; red[w * 2 + 1] = ss; }
    __syncthreads();
    if (t == 0) {
        float tc = 0.0f, ts = 0.0f;
        for (int k = 0; k < 4; ++k) { tc += red[k * 2]; ts += red[k * 2 + 1]; }
        tc /= (float)NOSC;
        ts /= (float)NOSC;
        coh[b] = sqrtf(tc * tc + ts * ts);
    }
}

extern "C" void kernel_launch(void* const* d_in, const int* in_sizes, int n_in,
                              void* d_out, int out_size, void* d_ws, size_t ws_size,
                              hipStream_t stream) {
    const float* theta_in = (const float*)d_in[0];
    const float* Kmat     = (const float*)d_in[1];
    const float* omega    = (const float*)d_in[2];
    const float* kg       = (const float*)d_in[3];
    const float* mod      = (const float*)d_in[4];

    float* th  = (float*)d_out;               // [NB][NOSC] final theta
    float* coh = (float*)d_out + M_TOT;       // [NB]

    unsigned short* Kb = (unsigned short*)d_ws;                       // 8 MB
    unsigned short* R0 = (unsigned short*)d_ws + (size_t)NOSC * NOSC; // 128 KB
    unsigned short* R1 = R0 + 2 * M_TOT;                              // 128 KB

    init_kernel<<<32, 256, 0, stream>>>(theta_in, th, R0);

    for (int s = 0; s < 10; ++s) {
        const unsigned short* rc = (s & 1) ? R1 : R0;
        unsigned short* rn = (s & 1) ? R0 : R1;
        if (s == 0)
            step_kernel<true, false><<<NOSC / 16, 1024, 0, stream>>>(
                Kmat, Kb, rc, rn, omega, kg, mod, th);
        else if (s < 9)
            step_kernel<false, false><<<NOSC / 16, 1024, 0, stream>>>(
                Kmat, Kb, rc, rn, omega, kg, mod, th);
        else
            step_kernel<false, true><<<NOSC / 16, 1024, 0, stream>>>(
                Kmat, Kb, rc, rn, omega, kg, mod, th);
    }

    // after 10 steps the live buffer is R0
    coherence_kernel<<<NB, 256, 0, stream>>>(R0, coh);
}

// Round 11
// 92.713 us; speedup vs baseline: 9.3676x; 1.0141x over previous
//
#include <hip/hip_runtime.h>
#include <math.h>

#define NOSC 2048
#define NB 16
#define DT 0.1f
#define M_TOT (NB * NOSC)    // 32768
#define KTP 2056             // padded LDS K row

typedef __attribute__((ext_vector_type(8))) short bf16x8;
typedef __attribute__((ext_vector_type(4))) float f32x4;

__device__ __forceinline__ unsigned short f2bf(float x) {
    unsigned int u = __float_as_uint(x);
    u += 0x7FFFu + ((u >> 16) & 1u);          // round-to-nearest-even
    return (unsigned short)(u >> 16);
}
__device__ __forceinline__ float bf2f(unsigned short u) {
    return __uint_as_float(((unsigned int)u) << 16);
}

// ws layout: Kb[2048][2048] bf16 (8 MB) | R0 [32][2048] bf16 | R1
// R rows 0..15 = sin(theta[b][:]), rows 16..31 = cos.

// ---------- init: copy theta, build R0 (32 blocks x 256) ----------
__global__ void init_kernel(const float* __restrict__ th_in,
                            float* __restrict__ th,
                            unsigned short* __restrict__ R0) {
    const int o4 = (blockIdx.x * 256 + threadIdx.x) * 4;
    if (o4 < M_TOT) {
        float4 v = *reinterpret_cast<const float4*>(th_in + o4);
        *reinterpret_cast<float4*>(th + o4) = v;
        float s0, c0, s1, c1, s2, c2, s3, c3;
        sincosf(v.x, &s0, &c0); sincosf(v.y, &s1, &c1);
        sincosf(v.z, &s2, &c2); sincosf(v.w, &s3, &c3);
        ushort4 us = {f2bf(s0), f2bf(s1), f2bf(s2), f2bf(s3)};
        ushort4 uc = {f2bf(c0), f2bf(c1), f2bf(c2), f2bf(c3)};
        *reinterpret_cast<ushort4*>(R0 + o4) = us;
        *reinterpret_cast<ushort4*>(R0 + M_TOT + o4) = uc;
    }
}

// ---------- fused MFMA step ----------
// Grid 128, block 1024 = 16 waves. Block owns i in [bx*16, bx*16+16).
// Wave w = kq (k-sixteenth, 128 k = 4 MFMA iters of K=32), computes BOTH
// c-halves sharing one B fragment. ALL 12 fragments (48 VGPR) are loaded
// upfront -> single L2 latency exposure, then 8 back-to-back MFMAs.
// Update inputs (th, sin_i, cos_i, omega) prefetched before the MFMA phase.
template <bool FIRST, bool FINAL>
__global__ __launch_bounds__(1024, 4) void step_kernel(
    const float* __restrict__ Kmat,
    unsigned short* __restrict__ Kb,
    const unsigned short* __restrict__ Rc,
    unsigned short* __restrict__ Rn,
    const float* __restrict__ omega,
    const float* __restrict__ kg,
    const float* __restrict__ mod,
    float* __restrict__ th)
{
    __shared__ float part[16][2][64][4];            // 32 KB
    __shared__ float coup[32][16];                  // 2 KB

    const int t = threadIdx.x;
    const int lane = t & 63;
    const int w = t >> 6;                            // wave = kq, 0..15
    const int i0 = blockIdx.x * 16;

    // ---- prefetch theta-update inputs (waves 0..3) ----
    float th_o = 0.0f, sin_i = 0.0f, cos_i = 0.0f, om_i = 0.0f;
    size_t o_upd = 0;
    if (t < 256) {
        const int b2 = t >> 4;
        const int il = t & 15;
        o_upd = (size_t)b2 * NOSC + (i0 + il);
        th_o = th[o_upd];
        sin_i = bf2f(Rc[o_upd]);
        cos_i = bf2f(Rc[M_TOT + o_upd]);
        om_i = omega[i0 + il];
    }
    const float scale = kg[0] * (1.0f + mod[0]) * (1.0f / (float)NOSC);

    const int rl = lane & 15;
    const int kbase = w * 128 + ((lane >> 4) << 3);

    const unsigned short* __restrict__ pas = Rc + (size_t)rl * NOSC + kbase;
    const unsigned short* __restrict__ pac = Rc + (size_t)(16 + rl) * NOSC + kbase;

    bf16x8 as[4], ac[4], bb[4];

    if constexpr (FIRST) {
        __shared__ unsigned short Kt[16][KTP];       // 64.25 KB (step 0 only)
        const float4* __restrict__ src =
            reinterpret_cast<const float4*>(Kmat + (size_t)i0 * NOSC);
#pragma unroll
        for (int p = 0; p < 8; ++p) {
            const int q = t + p * 1024;              // float4 index 0..8191
            float4 v = src[q];
            ushort4 u = {f2bf(v.x), f2bf(v.y), f2bf(v.z), f2bf(v.w)};
            const int row = q >> 9;
            const int col = (q & 511) * 4;
            *reinterpret_cast<ushort4*>(&Kt[row][col]) = u;
            *reinterpret_cast<ushort4*>(Kb + (size_t)(i0 + row) * NOSC + col) = u;
        }
        __syncthreads();
#pragma unroll
        for (int it = 0; it < 4; ++it)
            bb[it] = *reinterpret_cast<const bf16x8*>(&Kt[rl][kbase + it * 32]);
    } else {
        const unsigned short* __restrict__ pbg =
            Kb + (size_t)(i0 + rl) * NOSC + kbase;
#pragma unroll
        for (int it = 0; it < 4; ++it)
            bb[it] = *reinterpret_cast<const bf16x8*>(pbg + it * 32);
    }

    // ---- all A fragments upfront (8 loads; with B = 12 in flight) ----
#pragma unroll
    for (int it = 0; it < 4; ++it) {
        as[it] = *reinterpret_cast<const bf16x8*>(pas + it * 32);
        ac[it] = *reinterpret_cast<const bf16x8*>(pac + it * 32);
    }

    f32x4 acc_s = {0.0f, 0.0f, 0.0f, 0.0f};
    f32x4 acc_c = {0.0f, 0.0f, 0.0f, 0.0f};
#pragma unroll
    for (int it = 0; it < 4; ++it) {
        acc_s = __builtin_amdgcn_mfma_f32_16x16x32_bf16(as[it], bb[it], acc_s, 0, 0, 0);
        acc_c = __builtin_amdgcn_mfma_f32_16x16x32_bf16(ac[it], bb[it], acc_c, 0, 0, 0);
    }

    *reinterpret_cast<f32x4*>(&part[w][0][lane][0]) = acc_s;
    *reinterpret_cast<f32x4*>(&part[w][1][lane][0]) = acc_c;
    __syncthreads();

    // reduce 16 kq-partials: cell (c, il), c = half*16 + (ln>>4)*4 + rg
    if (t < 512) {
        const int c = t >> 4;            // 0..31
        const int il = t & 15;
        const int half = c >> 4;
        const int cl = c & 15;
        const int ln = ((cl >> 2) << 4) | il;
        const int rg = cl & 3;
        float s = 0.0f;
#pragma unroll
        for (int q = 0; q < 16; ++q) s += part[q][half][ln][rg];
        coup[c][il] = s;
    }
    __syncthreads();

    // theta update for this block's 256 (b, i) — inputs already in registers
    if (t < 256) {
        const int b2 = t >> 4;
        const int il = t & 15;
        const float aS = coup[b2][il];
        const float aC = coup[16 + b2][il];
        float nt = th_o + DT * (om_i + scale * (cos_i * aS - sin_i * aC));
        float ws, wc;
        sincosf(nt, &ws, &wc);
        // wrap only shifts theta by 2*pi*k -> sin/cos unchanged; defer atan2
        th[o_upd] = FINAL ? atan2f(ws, wc) : nt;
        Rn[o_upd] = f2bf(ws);
        Rn[M_TOT + o_upd] = f2bf(wc);
    }
}

// ---------- coherence from final R (bf16) ----------
__global__ void coherence_kernel(const unsigned short* __restrict__ R,
                                 float* __restrict__ coh) {
    const int b = blockIdx.x;
    const int t = threadIdx.x;
    float ss = 0.0f, sc = 0.0f;
    for (int j = t; j < NOSC; j += 256) {
        ss += bf2f(R[(size_t)b * NOSC + j]);
        sc += bf2f(R[M_TOT + (size_t)b * NOSC + j]);
    }
    for (int off = 32; off > 0; off >>= 1) {
        ss += __shfl_down(ss, off);
        sc += __shfl_down(sc, off);
    }
    __shared__ float red[8];
    const int w = t >> 6;
    if ((t & 63) == 0) { red[w * 2] = sc; red[w * 2 + 1] = ss; }
    __syncthreads();
    if (t == 0) {
        float tc = 0.0f, ts = 0.0f;
        for (int k = 0; k < 4; ++k) { tc += red[k * 2]; ts += red[k * 2 + 1]; }
        tc /= (float)NOSC;
        ts /= (float)NOSC;
        coh[b] = sqrtf(tc * tc + ts * ts);
    }
}

extern "C" void kernel_launch(void* const* d_in, const int* in_sizes, int n_in,
                              void* d_out, int out_size, void* d_ws, size_t ws_size,
                              hipStream_t stream) {
    const float* theta_in = (const float*)d_in[0];
    const float* Kmat     = (const float*)d_in[1];
    const float* omega    = (const float*)d_in[2];
    const float* kg       = (const float*)d_in[3];
    const float* mod      = (const float*)d_in[4];

    float* th  = (float*)d_out;               // [NB][NOSC] final theta
    float* coh = (float*)d_out + M_TOT;       // [NB]

    unsigned short* Kb = (unsigned short*)d_ws;                       // 8 MB
    unsigned short* R0 = (unsigned short*)d_ws + (size_t)NOSC * NOSC; // 128 KB
    unsigned short* R1 = R0 + 2 * M_TOT;                              // 128 KB

    init_kernel<<<32, 256, 0, stream>>>(theta_in, th, R0);

    for (int s = 0; s < 10; ++s) {
        const unsigned short* rc = (s & 1) ? R1 : R0;
        unsigned short* rn = (s & 1) ? R0 : R1;
        if (s == 0)
            step_kernel<true, false><<<NOSC / 16, 1024, 0, stream>>>(
                Kmat, Kb, rc, rn, omega, kg, mod, th);
        else if (s < 9)
            step_kernel<false, false><<<NOSC / 16, 1024, 0, stream>>>(
                Kmat, Kb, rc, rn, omega, kg, mod, th);
        else
            step_kernel<false, true><<<NOSC / 16, 1024, 0, stream>>>(
                Kmat, Kb, rc, rn, omega, kg, mod, th);
    }

    // after 10 steps the live buffer is R0
    coherence_kernel<<<NB, 256, 0, stream>>>(R0, coh);
}